// Round 3
// baseline (297.217 us; speedup 1.0000x reference)
//
#include <hip/hip_runtime.h>

#define T_DEPTH 200000
#define V_DIM   130
#define H_DIM   512

// d_out offsets (fp32 elements): ot, Val, stg, rt, h_new, c_new
#define OT_OFF   0
#define VAL_OFF  512
#define STG_OFF  26000642
#define RT_OFF   26200643
#define HN_OFF   26200773
#define CN_OFF   26201797

// copy index space: Val body as 16B units, stg as 8B units
#define NV4 6500000   // T*V/4
#define NS2 100000    // T/2
// static partition of the Val copy across the 4 kernels
#define A1  1625000
#define A2  3250000
#define A3  4875000
#define MVB 128       // blocks doing LSTM matvec in kernels 1-2 (128*4 waves = 512 units)
#define CPB 1536      // copy blocks appended to every kernel

// ext-vector types (required by __builtin_nontemporal_*; HIP float4 is a struct)
typedef float f32x4 __attribute__((ext_vector_type(4)));
typedef float f32x2 __attribute__((ext_vector_type(2)));

static __device__ __forceinline__ float sigmoidf_(float x) {
  return 1.0f / (1.0f + expf(-x));
}

// 4-deep unrolled streaming 16B copy of [lo,hi) by workers w in [0,S)
static __device__ __forceinline__ void copy_val4(const f32x4* __restrict__ vin,
                                                 f32x4* __restrict__ vout,
                                                 int lo, int hi, int w, int S) {
  int u = lo + w;
  for (; u + 3 * S < hi; u += 4 * S) {
    f32x4 a = __builtin_nontemporal_load(vin + u);
    f32x4 b = __builtin_nontemporal_load(vin + u + S);
    f32x4 c = __builtin_nontemporal_load(vin + u + 2 * S);
    f32x4 d = __builtin_nontemporal_load(vin + u + 3 * S);
    __builtin_nontemporal_store(a, vout + u);
    __builtin_nontemporal_store(b, vout + u + S);
    __builtin_nontemporal_store(c, vout + u + 2 * S);
    __builtin_nontemporal_store(d, vout + u + 3 * S);
  }
  for (; u < hi; u += S) {
    f32x4 a = __builtin_nontemporal_load(vin + u);
    __builtin_nontemporal_store(a, vout + u);
  }
}

// one wave computes all 4 gate dots for unit j, then lane 0 applies the cell.
// x = x_a (+ x_b if non-null), dims: Wih (4H, in_dim), Whh (4H, H)
static __device__ __forceinline__ void lstm_unit(
    const float* __restrict__ Wih, int in_dim,
    const float* __restrict__ x_a, const float* __restrict__ x_b,
    const float* __restrict__ Whh, const float* __restrict__ hprev,
    const float* __restrict__ bih, const float* __restrict__ bhh,
    const float* __restrict__ cprev, int j, int lane,
    float* __restrict__ h_out, float* __restrict__ c_out) {
  float pg[4];
#pragma unroll
  for (int q = 0; q < 4; ++q) {
    int row = q * H_DIM + j;
    const float* wr = Wih + row * in_dim;
    const float* wh = Whh + row * H_DIM;
    float acc = 0.f;
    if (x_b) {
      for (int c = lane; c < in_dim; c += 64) acc += wr[c] * (x_a[c] + x_b[c]);
    } else {
      for (int c = lane; c < in_dim; c += 64) acc += wr[c] * x_a[c];
    }
    for (int k = lane; k < H_DIM; k += 64) acc += wh[k] * hprev[k];
    for (int off = 32; off; off >>= 1) acc += __shfl_down(acc, off, 64);
    pg[q] = acc;  // total valid on lane 0
  }
  if (lane == 0) {
    float ig = sigmoidf_(pg[0] + bih[j] + bhh[j]);
    float fg = sigmoidf_(pg[1] + bih[H_DIM + j] + bhh[H_DIM + j]);
    float gg = tanhf(pg[2] + bih[2 * H_DIM + j] + bhh[2 * H_DIM + j]);
    float og = sigmoidf_(pg[3] + bih[3 * H_DIM + j] + bhh[3 * H_DIM + j]);
    float cn = fg * cprev[j] + ig * gg;
    float hn = og * tanhf(cn);
    h_out[j] = hn;
    c_out[j] = cn;
  }
}

// ---- kernel 1: L0 LSTM (blocks [0,MVB)) || copy all stg + Val slice [0,A1)
__global__ void k1_l0(const float* __restrict__ Wih, const float* __restrict__ Whh,
                      const float* __restrict__ bih, const float* __restrict__ bhh,
                      const float* __restrict__ inp, const float* __restrict__ prd,
                      const float* __restrict__ hprev, const float* __restrict__ cprev,
                      const f32x4* __restrict__ vin, const f32x2* __restrict__ sin2,
                      float* __restrict__ out) {
  int bid = blockIdx.x, tid = threadIdx.x;
  if (bid < MVB) {
    lstm_unit(Wih, V_DIM, inp, prd, Whh, hprev, bih, bhh, cprev,
              bid * 4 + (tid >> 6), tid & 63, out + HN_OFF, out + CN_OFF);
  } else {
    int w = (bid - MVB) * 256 + tid;
    int S = (gridDim.x - MVB) * 256;
    f32x2* __restrict__ sout = reinterpret_cast<f32x2*>(out + STG_OFF);
    for (int u = w; u < NS2; u += S) {
      f32x2 sv = __builtin_nontemporal_load(sin2 + u);
      __builtin_nontemporal_store(sv, sout + u);
    }
    copy_val4(vin, reinterpret_cast<f32x4*>(out + VAL_OFF), 0, A1, w, S);
  }
}

// ---- kernel 2: L1 LSTM || copy Val slice [A1,A2)
__global__ void k2_l1(const float* __restrict__ Wih, const float* __restrict__ Whh,
                      const float* __restrict__ bih, const float* __restrict__ bhh,
                      const float* __restrict__ hprev, const float* __restrict__ cprev,
                      const f32x4* __restrict__ vin, float* __restrict__ out) {
  int bid = blockIdx.x, tid = threadIdx.x;
  if (bid < MVB) {
    lstm_unit(Wih, H_DIM, out + HN_OFF, nullptr, Whh, hprev, bih, bhh, cprev,
              bid * 4 + (tid >> 6), tid & 63,
              out + HN_OFF + H_DIM, out + CN_OFF + H_DIM);
  } else {
    int w = (bid - MVB) * 256 + tid;
    int S = (gridDim.x - MVB) * 256;
    copy_val4(vin, reinterpret_cast<f32x4*>(out + VAL_OFF), A1, A2, w, S);
  }
}

// ---- kernel 3: heads (blocks 0..3, column-owner dots) || copy Val slice [A2,A3)
__global__ void k3_heads(const float* __restrict__ Wv, const float* __restrict__ Bv,
                         const float* __restrict__ Wo, const float* __restrict__ Bo,
                         const float* __restrict__ Wd, const float* __restrict__ Bd,
                         const float* __restrict__ Wu, const float* __restrict__ Bu,
                         const f32x4* __restrict__ vin, float* __restrict__ ws,
                         float* __restrict__ out) {
  int bid = blockIdx.x, tid = threadIdx.x;
  const float* h2 = out + HN_OFF + H_DIM;
  if (bid < 2) {
    int t = bid * 256 + tid;
    float a0 = 0.f, a1 = 0.f, a2 = 0.f, a3 = 0.f;
    for (int k = 0; k < H_DIM; k += 4) {
      a0 += h2[k]     * Wo[k * H_DIM + t];
      a1 += h2[k + 1] * Wo[(k + 1) * H_DIM + t];
      a2 += h2[k + 2] * Wo[(k + 2) * H_DIM + t];
      a3 += h2[k + 3] * Wo[(k + 3) * H_DIM + t];
    }
    out[OT_OFF + t] = tanhf(((a0 + a1) + (a2 + a3)) + Bo[t]);
  } else if (bid == 2) {
    if (tid < V_DIM) {
      float a0 = 0.f, a1 = 0.f, a2 = 0.f, a3 = 0.f;
      for (int k = 0; k < H_DIM; k += 4) {
        a0 += h2[k]     * Wv[k * V_DIM + tid];
        a1 += h2[k + 1] * Wv[(k + 1) * V_DIM + tid];
        a2 += h2[k + 2] * Wv[(k + 2) * V_DIM + tid];
        a3 += h2[k + 3] * Wv[(k + 3) * V_DIM + tid];
      }
      out[VAL_OFF + T_DEPTH * V_DIM + tid] = tanhf(((a0 + a1) + (a2 + a3)) + Bv[tid]);
    }
  } else if (bid == 3) {
    int wid = tid >> 6, lane = tid & 63;
    if (wid < 2) {
      const float* wv = (wid == 0) ? Wd : Wu;
      float acc = 0.f;
      for (int k = lane; k < H_DIM; k += 64) acc += h2[k] * wv[k];
      for (int off = 32; off; off >>= 1) acc += __shfl_down(acc, off, 64);
      if (lane == 0) {
        if (wid == 0) {
          float dt = sigmoidf_(acc + Bd[0]);
          ws[0] = dt;
          out[STG_OFF + T_DEPTH] = dt;       // stg[T] = dt
        } else {
          ws[1] = sigmoidf_(acc + Bu[0]);    // ut
        }
      }
    }
  } else {
    int w = (bid - 4) * 256 + tid;
    int S = (gridDim.x - 4) * 256;
    copy_val4(vin, reinterpret_cast<f32x4*>(out + VAL_OFF), A2, A3, w, S);
  }
}

// ---- kernel 4: exact top-of-stack walk (block 0) || copy Val slice [A3,NV4)
__global__ void k4_top(const float* __restrict__ prev_stg, const float* __restrict__ prev_val,
                       const float* __restrict__ ws, const f32x4* __restrict__ vin,
                       float* __restrict__ out) {
  int bid = blockIdx.x, t = threadIdx.x;
  if (bid == 0) {
    float dt = ws[0];
    float u  = ws[1];   // pop carry (starts at ut)
    float r  = 1.0f;    // read carry
    float acc = 0.f;
    {  // i = T (freshly pushed row): stg[T]=dt already written, vt in out row T
      float coef = fminf(dt, fmaxf(0.f, r));
      if (t < V_DIM) acc += coef * out[VAL_OFF + T_DEPTH * V_DIM + t];
      r -= dt;
    }
    for (int i = T_DEPTH - 1; i >= 0; --i) {
      bool pop_active = (u > 0.f);
      if (!pop_active && r <= 0.f) break;   // below: sn == s (bulk copy correct), coef == 0
      float s  = prev_stg[i];               // wave-uniform load
      float sn = fmaxf(0.f, s - fmaxf(0.f, u));
      u -= sn;
      if (pop_active && t == 0) out[STG_OFF + i] = sn;
      float coef = fminf(sn, fmaxf(0.f, r));
      r -= sn;
      if (coef > 0.f && t < V_DIM) acc += coef * prev_val[i * V_DIM + t];
    }
    if (t < V_DIM) out[RT_OFF + t] = acc;
  } else {
    int w = (bid - 1) * 256 + t;
    int S = (gridDim.x - 1) * 256;
    copy_val4(vin, reinterpret_cast<f32x4*>(out + VAL_OFF), A3, NV4, w, S);
  }
}

extern "C" void kernel_launch(void* const* d_in, const int* in_sizes, int n_in,
                              void* d_out, int out_size, void* d_ws, size_t ws_size,
                              hipStream_t stream) {
  (void)in_sizes; (void)n_in; (void)out_size; (void)ws_size;
  const float* input     = (const float*)d_in[0];
  const float* prev_Val  = (const float*)d_in[1];
  const float* prev_stg  = (const float*)d_in[2];
  const float* prev_read = (const float*)d_in[3];
  const float* prev_h    = (const float*)d_in[4];
  const float* prev_c    = (const float*)d_in[5];
  const float* W_ih0 = (const float*)d_in[6];
  const float* W_hh0 = (const float*)d_in[7];
  const float* b_ih0 = (const float*)d_in[8];
  const float* b_hh0 = (const float*)d_in[9];
  const float* W_ih1 = (const float*)d_in[10];
  const float* W_hh1 = (const float*)d_in[11];
  const float* b_ih1 = (const float*)d_in[12];
  const float* b_hh1 = (const float*)d_in[13];
  const float* Wd = (const float*)d_in[14];
  const float* Bd = (const float*)d_in[15];
  const float* Wu = (const float*)d_in[16];
  const float* Bu = (const float*)d_in[17];
  const float* Wv = (const float*)d_in[18];
  const float* Bv = (const float*)d_in[19];
  const float* Wo = (const float*)d_in[20];
  const float* Bo = (const float*)d_in[21];

  float* out = (float*)d_out;
  float* ws  = (float*)d_ws;  // only ws[0..1] used (dt, ut) — write-before-read

  const f32x4* vin = (const f32x4*)prev_Val;
  const f32x2* sin2 = (const f32x2*)prev_stg;

  // dependency chain ordered by the stream; each kernel also carries a slice
  // of the independent Val copy so the copy overlaps the whole chain.
  k1_l0<<<MVB + CPB, 256, 0, stream>>>(W_ih0, W_hh0, b_ih0, b_hh0, input, prev_read,
                                       prev_h, prev_c, vin, sin2, out);
  k2_l1<<<MVB + CPB, 256, 0, stream>>>(W_ih1, W_hh1, b_ih1, b_hh1,
                                       prev_h + H_DIM, prev_c + H_DIM, vin, out);
  k3_heads<<<4 + CPB, 256, 0, stream>>>(Wv, Bv, Wo, Bo, Wd, Bd, Wu, Bu, vin, ws, out);
  k4_top<<<1 + CPB, 256, 0, stream>>>(prev_stg, prev_Val, ws, vin, out);
}